// Round 11
// baseline (5910.638 us; speedup 1.0000x reference)
//
#include <hip/hip_runtime.h>
#include <math.h>

#define B_N 32
#define T_N 1024
#define E_N 512
#define H_N 512

typedef __attribute__((ext_vector_type(8))) short short8;
typedef __attribute__((ext_vector_type(4))) float f32x4;
typedef __attribute__((ext_vector_type(4))) unsigned int uint32x4;
typedef unsigned long long ull;

__device__ __forceinline__ unsigned short f2bfu(float f) {
  unsigned int x = __builtin_bit_cast(unsigned int, f);
  x += 0x7fffu + ((x >> 16) & 1u);
  return (unsigned short)(x >> 16);
}
__device__ __forceinline__ float bfu2f(unsigned short u) {
  return __builtin_bit_cast(float, ((unsigned int)u) << 16);
}
__device__ __forceinline__ float sigmf(float x) { return 1.0f / (1.0f + expf(-x)); }

// ---- agent-scope (MALL-coherent, bypass L1/L2) helpers (R8, verified) -----
__device__ __forceinline__ void load64_mall(const unsigned short* p,
                                            uint32x4& a, uint32x4& b,
                                            uint32x4& c, uint32x4& d) {
  asm volatile("global_load_dwordx4 %0, %4, off sc0 sc1\n\t"
               "global_load_dwordx4 %1, %4, off offset:16 sc0 sc1\n\t"
               "global_load_dwordx4 %2, %4, off offset:32 sc0 sc1\n\t"
               "global_load_dwordx4 %3, %4, off offset:48 sc0 sc1\n\t"
               "s_waitcnt vmcnt(0)"
               : "=&v"(a), "=&v"(b), "=&v"(c), "=&v"(d)
               : "v"(p) : "memory");
}
__device__ __forceinline__ void store32_mall(unsigned int* p, unsigned int v) {
  asm volatile("global_store_dword %0, %1, off sc0 sc1" :: "v"(p), "v"(v) : "memory");
}
// Pipelined 2-deep flag poll (R8). On exit up to ONE flag load outstanding —
// drained by load64_mall's internal vmcnt(0) before any data use.
__device__ __forceinline__ void poll_flag2(const unsigned int* pf, unsigned int want) {
  unsigned int fa, fb;
  asm volatile("global_load_dword %0, %2, off sc0 sc1\n\t"
               "global_load_dword %1, %2, off sc0 sc1"
               : "=&v"(fa), "=&v"(fb) : "v"(pf) : "memory");
  for (;;) {
    asm volatile("s_waitcnt vmcnt(1)" ::: "memory");
    __builtin_amdgcn_sched_barrier(0);
    if (fa >= want) break;
    asm volatile("global_load_dword %0, %1, off sc0 sc1" : "=&v"(fa) : "v"(pf) : "memory");
    asm volatile("s_waitcnt vmcnt(1)" ::: "memory");
    __builtin_amdgcn_sched_barrier(0);
    if (fb >= want) break;
    asm volatile("global_load_dword %0, %1, off sc0 sc1" : "=&v"(fb) : "v"(pf) : "memory");
  }
}

// ---------------------------------------------------------------------------
// Persistent BiLSTM: 64 wgs x 512 threads, dir = wg&1, cg = wg>>1 (16 cols).
// R8 transport (per-wave flags + bulk MALL h exchange) — UNCHANGED.
// NEW: x-projection computed on the fly. Per step, gates =
//   h(t) @ Whh_slice^T  +  xs_row(t) @ Wih_slice^T  + bias,
// both MFMA'd from LDS tiles; Whh/Wih fragments live in registers.
// xs(t+1) rows are recurrence-independent: 8xfloat4/thread issued at step
// top (latency hidden under the poll; S1's barrier drain guarantees arrival),
// converted to bf16 and ds_written into the double-buffered Xs tile at S1.
// Logits: per-step __shfl_xor reduce over the wg's 16 cols (no LDS pass).
// Early stop at Lmax = lengths[0] (sorted descending): steps t >= Lmax are
// provable no-ops (all-masked; outputs = softmax(b_cls) via lpart zeros).
// ---------------------------------------------------------------------------
__global__ __launch_bounds__(512, 1) void rec_kernel(
    const float* __restrict__ xs, const int* __restrict__ lengths,
    const float* __restrict__ w_ih_f, const float* __restrict__ b_f,
    const float* __restrict__ w_ih_b, const float* __restrict__ b_b,
    const float* __restrict__ w_hh_f, const float* __restrict__ w_hh_b,
    const float* __restrict__ w_cls,
    unsigned short* __restrict__ hx,         // [2][2][32][32][16] bf16
    unsigned int* __restrict__ flg,          // [2][32][8] u32
    float* __restrict__ lpart)               // [64 wg][B][T][2]
{
  __shared__ unsigned short Ah[32][520];       // 33.3 KB
  __shared__ unsigned short Xs2[2][32][520];   // 66.6 KB (double-buffered xs)
  __shared__ float gate_p[8][32][17];          // 17.4 KB

  const int tid = threadIdx.x;
  const int wg = blockIdx.x;
  const int dir = wg & 1;
  const int cg = wg >> 1;
  const int colbase = cg * 16;
  const float* __restrict__ w_hh = dir ? w_hh_b : w_hh_f;
  const float* __restrict__ w_ih = dir ? w_ih_b : w_ih_f;
  const float* __restrict__ bias = dir ? b_b : b_f;
  const int w = tid >> 6, lane = tid & 63;
  const int q = w >> 1, kh = w & 1;
  const int Lmax = lengths[0];                 // sorted descending -> max
  const int Tloc = (Lmax < T_N) ? Lmax : T_N;

  // one-time: W_hh and W_ih fragments (gate q, K-half kh) into registers
  short8 whh[8], wih[8];
  {
    const int grow = q * 512 + colbase + (lane & 15);
    const int kb = (lane >> 4) << 3;
    const float* __restrict__ rh = &w_hh[(size_t)grow * H_N + kh * 256];
    const float* __restrict__ ri = &w_ih[(size_t)grow * E_N + kh * 256];
#pragma unroll
    for (int ks = 0; ks < 8; ++ks) {
      float4 f0 = *(const float4*)&rh[ks * 32 + kb];
      float4 f1 = *(const float4*)&rh[ks * 32 + kb + 4];
      short8 v;
      v[0] = (short)f2bfu(f0.x); v[1] = (short)f2bfu(f0.y);
      v[2] = (short)f2bfu(f0.z); v[3] = (short)f2bfu(f0.w);
      v[4] = (short)f2bfu(f1.x); v[5] = (short)f2bfu(f1.y);
      v[6] = (short)f2bfu(f1.z); v[7] = (short)f2bfu(f1.w);
      whh[ks] = v;
      f0 = *(const float4*)&ri[ks * 32 + kb];
      f1 = *(const float4*)&ri[ks * 32 + kb + 4];
      v[0] = (short)f2bfu(f0.x); v[1] = (short)f2bfu(f0.y);
      v[2] = (short)f2bfu(f0.z); v[3] = (short)f2bfu(f0.w);
      v[4] = (short)f2bfu(f1.x); v[5] = (short)f2bfu(f1.y);
      v[6] = (short)f2bfu(f1.z); v[7] = (short)f2bfu(f1.w);
      wih[ks] = v;
    }
  }

  // per-thread epilogue ownership: b = tid>>4 (32), cl = tid&15 (16 cols)
  const int b = tid >> 4;
  const int cl = tid & 15;
  const int col = colbase + cl;
  const int Lb = lengths[b];
  float cc = 0.f, hh = 0.f;
  const float wc0 = w_cls[dir * H_N + col];
  const float wc1 = w_cls[2 * H_N + dir * H_N + col];
  const float bi  = bias[col];
  const float bff = bias[512 + col];
  const float bg  = bias[1024 + col];
  const float bo  = bias[1536 + col];

  float* __restrict__ lslice = lpart + (size_t)wg * B_N * T_N * 2;
  unsigned int* __restrict__ myflag = flg + ((size_t)dir * 32 + cg) * 8 + w;
  const unsigned int* __restrict__ pollflag =
      flg + ((size_t)dir * 32 + (tid >> 4)) * 8 + ((tid & 15) >> 1);

  const int b0 = (tid & 15) * 2, cg16 = (tid >> 4) * 16;

  // xs staging role: this thread stages batch b, E-chunk [cl*32, cl*32+32)
  // prologue: stage xs(t=0) into Xs2[0]
  {
    const int srcT = 0;  // fwd t=0; bwd t=0 -> Lb-1-0 if 0<Lb (always)
    const int st = dir ? (Lb - 1) : srcT;
    const float* __restrict__ xrow = xs + ((size_t)b * T_N + st) * E_N + cl * 32;
    unsigned short* __restrict__ dst = &Xs2[0][b][cl * 32];
#pragma unroll
    for (int i = 0; i < 8; ++i) {
      const float4 v = *(const float4*)&xrow[i * 4];
      ushort4 u;
      u.x = f2bfu(v.x); u.y = f2bfu(v.y); u.z = f2bfu(v.z); u.w = f2bfu(v.w);
      *(ushort4*)&dst[i * 4] = u;
    }
  }
  __syncthreads();

  for (int ts = 0; ts < Tloc; ++ts) {
    const int t = ts;

    // A: issue xs loads for t+1 (recurrence-independent; hidden under poll)
    float4 av[8];
    const bool pfv = (ts + 1 < Tloc);
    if (pfv) {
      const int tn = t + 1;
      const int st = (dir && tn < Lb) ? (Lb - 1 - tn) : tn;
      const float* __restrict__ xrow = xs + ((size_t)b * T_N + st) * E_N + cl * 32;
#pragma unroll
      for (int i = 0; i < 8; ++i) av[i] = *(const float4*)&xrow[i * 4];
    }

    // B: wait for producer wave covering this thread's slice; bulk h load
    poll_flag2(pollflag, (unsigned int)t);
    {
      uint32x4 va, vb, vc, vd;
      load64_mall(hx + ((size_t)dir * 2 + (t & 1)) * 16384 + (size_t)tid * 32,
                  va, vb, vc, vd);
      *(uint32x4*)&Ah[b0][cg16] = va;
      *(uint32x4*)&Ah[b0][cg16 + 8] = vb;
      *(uint32x4*)&Ah[b0 + 1][cg16] = vc;
      *(uint32x4*)&Ah[b0 + 1][cg16 + 8] = vd;
    }
    __syncthreads();  // S1: Ah complete; av[] loads drained by barrier

    // C: stage xs(t+1) into the other Xs buffer (av registers die here)
    if (pfv) {
      unsigned short* __restrict__ dst = &Xs2[(t + 1) & 1][b][cl * 32];
#pragma unroll
      for (int i = 0; i < 8; ++i) {
        ushort4 u;
        u.x = f2bfu(av[i].x); u.y = f2bfu(av[i].y);
        u.z = f2bfu(av[i].z); u.w = f2bfu(av[i].w);
        *(ushort4*)&dst[i * 4] = u;
      }
    }

    // D: MFMA — wave w: gate q, K-half kh; h-term + x-term
    {
      f32x4 acc0 = {0.f, 0.f, 0.f, 0.f}, acc1 = {0.f, 0.f, 0.f, 0.f};
      const int kb = (lane >> 4) << 3;
      const unsigned short (*Xc)[520] = Xs2[t & 1];
#pragma unroll
      for (int ks = 0; ks < 8; ++ks) {
        const int kk = kh * 256 + (ks << 5) + kb;
        short8 a0 = *(const short8*)&Ah[(lane & 15)][kk];
        short8 a1 = *(const short8*)&Ah[16 + (lane & 15)][kk];
        acc0 = __builtin_amdgcn_mfma_f32_16x16x32_bf16(a0, whh[ks], acc0, 0, 0, 0);
        acc1 = __builtin_amdgcn_mfma_f32_16x16x32_bf16(a1, whh[ks], acc1, 0, 0, 0);
        short8 x0 = *(const short8*)&Xc[(lane & 15)][kk];
        short8 x1 = *(const short8*)&Xc[16 + (lane & 15)][kk];
        acc0 = __builtin_amdgcn_mfma_f32_16x16x32_bf16(x0, wih[ks], acc0, 0, 0, 0);
        acc1 = __builtin_amdgcn_mfma_f32_16x16x32_bf16(x1, wih[ks], acc1, 0, 0, 0);
      }
      const int crow = (lane >> 4) << 2;
      const int ccol = lane & 15;
#pragma unroll
      for (int j = 0; j < 4; ++j) {
        gate_p[w][crow + j][ccol] = acc0[j];
        gate_p[w][16 + crow + j][ccol] = acc1[j];
      }
    }
    __syncthreads();  // S2: gate_p ready

    // E: epilogue — merge K-halves, add bias, state update (fp32)
    const bool valid = (t < Lb);
    float hn;
    {
      const float gi = gate_p[0][b][cl] + gate_p[1][b][cl] + bi;
      const float gf = gate_p[2][b][cl] + gate_p[3][b][cl] + bff;
      const float gg = gate_p[4][b][cl] + gate_p[5][b][cl] + bg;
      const float go = gate_p[6][b][cl] + gate_p[7][b][cl] + bo;
      const float cn = sigmf(gf) * cc + sigmf(gi) * tanhf(gg);
      hn = sigmf(go) * tanhf(cn);
      if (valid) { cc = cn; hh = hn; }
    }

    // F: publish h pair (MALL write-through) + per-wave drain + flag
    {
      const float hhp = __shfl_xor(hh, 1);
      if ((cl & 1) == 0) {
        const unsigned int pv =
            (unsigned int)f2bfu(hh) | ((unsigned int)f2bfu(hhp) << 16);
        store32_mall((unsigned int*)(hx + ((size_t)dir * 2 + ((t + 1) & 1)) * 16384 +
                                     ((size_t)cg * 32 + b) * 16 + cl),
                     pv);
      }
    }
    asm volatile("s_waitcnt vmcnt(0)" ::: "memory");
    __builtin_amdgcn_sched_barrier(0);
    if (lane == 0)
      store32_mall(myflag, (unsigned int)(t + 1));

    // G: logits — shfl-reduce this wg's 16-col contribution, direct store
    {
      float l0 = valid ? hn * wc0 : 0.f;
      float l1 = valid ? hn * wc1 : 0.f;
#pragma unroll
      for (int m = 8; m >= 1; m >>= 1) {
        l0 += __shfl_xor(l0, m);
        l1 += __shfl_xor(l1, m);
      }
      if (cl == 0 && valid) {
        const int tpos = dir ? (Lb - 1 - t) : t;
        float2 v; v.x = l0; v.y = l1;
        *(float2*)&lslice[((size_t)b * T_N + tpos) * 2] = v;
      }
    }
  }
}

// ---------------------------------------------------------------------------
__global__ void init_kernel(ull* __restrict__ hx64, unsigned int* __restrict__ flg)
{
  const int i = blockIdx.x * 256 + threadIdx.x;  // 0..16383
  if (i < 16384) hx64[i] = 0ull;                 // hx: 128 KB of zeros
  if (i < 1024) flg[i] = 0u;
}

__global__ void reduce_softmax_kernel(const float* __restrict__ lpart,
                                      const float* __restrict__ b_cls,
                                      float* __restrict__ out)
{
  const int i = blockIdx.x * 256 + threadIdx.x;  // 0..32767
  if (i >= B_N * T_N) return;
  float s0 = b_cls[0], s1 = b_cls[1];
  const float* __restrict__ p = lpart + (size_t)i * 2;
#pragma unroll 8
  for (int wg = 0; wg < 64; ++wg) {
    s0 += p[(size_t)wg * B_N * T_N * 2];
    s1 += p[(size_t)wg * B_N * T_N * 2 + 1];
  }
  const float m = fmaxf(s0, s1);
  const float e0 = expf(s0 - m), e1 = expf(s1 - m);
  const float inv = 1.f / (e0 + e1);
  out[2 * i] = e0 * inv;
  out[2 * i + 1] = e1 * inv;
}

// ---------------------------------------------------------------------------
extern "C" void kernel_launch(void* const* d_in, const int* in_sizes, int n_in,
                              void* d_out, int out_size, void* d_ws, size_t ws_size,
                              hipStream_t stream)
{
  const float* xs      = (const float*)d_in[0];
  const int*   lengths = (const int*)d_in[1];
  // d_in[2] domains: unused (single-domain path)
  const float* w_ih_f  = (const float*)d_in[3];
  const float* w_hh_f  = (const float*)d_in[4];
  const float* b_f     = (const float*)d_in[5];
  const float* w_ih_b  = (const float*)d_in[6];
  const float* w_hh_b  = (const float*)d_in[7];
  const float* b_b     = (const float*)d_in[8];
  const float* w_cls   = (const float*)d_in[9];
  const float* b_cls   = (const float*)d_in[10];
  float* out = (float*)d_out;

  auto alignup = [](size_t v) { return (v + 255) & ~(size_t)255; };
  const size_t hx_b    = alignup((size_t)2 * 2 * 32 * 32 * 16 * 2);   // 128 KB
  const size_t flg_b   = alignup((size_t)1024 * 4);                   // 4 KB
  const size_t lpart_b = alignup((size_t)64 * B_N * T_N * 2 * 4);     // 16 MB

  char* p = (char*)d_ws;
  unsigned short* hx = (unsigned short*)p;  p += hx_b;
  unsigned int* flg = (unsigned int*)p;     p += flg_b;
  float* lpart = (float*)p;                 p += lpart_b;

  hipMemsetAsync(lpart, 0, lpart_b, stream);
  init_kernel<<<64, 256, 0, stream>>>((ull*)hx, flg);

  rec_kernel<<<64, 512, 0, stream>>>(xs, lengths, w_ih_f, b_f, w_ih_b, b_b,
                                     w_hh_f, w_hh_b, w_cls, hx, flg, lpart);

  reduce_softmax_kernel<<<128, 256, 0, stream>>>(lpart, b_cls, out);
}